// Round 15
// baseline (1252.280 us; speedup 1.0000x reference)
//
#include <hip/hip_runtime.h>
#include <math.h>

// FlowLayer: 2 steps of manifold (S^2) graph heat flow.
// N=50000 nodes, C=16 channels, D=3, E=1.6M edges.
//
// R15 restructure: coarse 64-node bucket binning instead of per-node CSR.
// pair entry packs [w:32][snd&63:6][rcv*48:26]; within-bucket order is
// irrelevant because the flow block accumulates into LDS by (snd&63, c).
// Build: bucket-count (LDS hist, 196 chunks) -> 3 tiny scan kernels ->
// bucket-scatter (LDS cursors, no per-edge pos). No global atomics, no
// memsets, ~1/3 the old build traffic and 5 launches fewer.
// Flow: block = bucket; p-slice + accumulators in LDS; ds_add_f32 accum;
// fused per-node update. Same R10 fp32 edge math (proven absmax 0.0039).
//
// NOTE: |u|^2 MUST be computed from u's components (not 1-cs^2): near
// antipodal pairs 1-cs^2 cancels catastrophically -> rsq explodes (R5 bug).

constexpr float EPS64F = 2.2204460492503131e-16f;  // np.float64 eps
constexpr float PI_F   = 3.14159265358979323846f;
constexpr int   BK_BITS = 6;    // 64 nodes per bucket
constexpr int   CH2     = 13;   // 8192 edges per chunk
constexpr int   NBMAX   = 4096; // supports N <= 262144

typedef int   vi4 __attribute__((ext_vector_type(4)));
typedef float vf4 __attribute__((ext_vector_type(4)));

// ---------------- bucket build ----------------

// Per-chunk bucket histogram (LDS), counts -> cnt[chunk][NB].
__global__ __launch_bounds__(256) void bincount_kernel(
    const int* __restrict__ snd, int* __restrict__ cnt, int E, int NB) {
  __shared__ int h[NBMAX];
  int tid = threadIdx.x, c = blockIdx.x;
  for (int i = tid; i < NB; i += 256) h[i] = 0;
  __syncthreads();
  int base = c << CH2;
  int n = min(1 << CH2, E - base);
  const vi4* s4 = (const vi4*)(snd + base);  // base is 8192-aligned
  int n4 = n >> 2;
  for (int i = tid; i < n4; i += 256) {
    vi4 v = __builtin_nontemporal_load(&s4[i]);
    atomicAdd(&h[v.x >> BK_BITS], 1);
    atomicAdd(&h[v.y >> BK_BITS], 1);
    atomicAdd(&h[v.z >> BK_BITS], 1);
    atomicAdd(&h[v.w >> BK_BITS], 1);
  }
  if (tid == 0) {
    for (int i = n4 << 2; i < n; ++i)
      atomicAdd(&h[snd[base + i] >> BK_BITS], 1);
  }
  __syncthreads();
  int* dst = cnt + (size_t)c * NB;
  for (int i = tid; i < NB; i += 256) dst[i] = h[i];
}

// Per-bucket totals over chunks (coalesced).
__global__ __launch_bounds__(256) void bintot_kernel(
    const int* __restrict__ cnt, int* __restrict__ tot, int NB, int NCH) {
  int b = blockIdx.x * 256 + threadIdx.x;
  if (b >= NB) return;
  int run = 0;
  for (int c = 0; c < NCH; ++c) run += cnt[(size_t)c * NB + b];
  tot[b] = run;
}

// One-wave exclusive scan of tot -> seg (bucket segment starts), seg[NB]=E.
__global__ __launch_bounds__(64) void binbase_kernel(
    const int* __restrict__ tot, int* __restrict__ seg, int NB) {
  int lane = threadIdx.x;
  int run = 0;
  for (int t0 = 0; t0 < NB; t0 += 64) {
    int i = t0 + lane;
    int v = (i < NB) ? tot[i] : 0;
    int incl = v;
    #pragma unroll
    for (int o = 1; o < 64; o <<= 1) {
      int t = __shfl_up(incl, o, 64);
      if (lane >= o) incl += t;
    }
    if (i < NB) seg[i] = run + incl - v;
    run += __shfl(incl, 63, 64);
  }
  if (lane == 0) seg[NB] = run;
}

// Per-(chunk,bucket) write offsets: off[c][b] = seg[b] + prefix over chunks.
__global__ __launch_bounds__(256) void binoff_kernel(
    const int* __restrict__ cnt, const int* __restrict__ seg,
    int* __restrict__ off, int NB, int NCH) {
  int b = blockIdx.x * 256 + threadIdx.x;
  if (b >= NB) return;
  int run = seg[b];
  for (int c = 0; c < NCH; ++c) {
    off[(size_t)c * NB + b] = run;
    run += cnt[(size_t)c * NB + b];
  }
}

// Scatter edges into bucket segments via LDS cursors (no global atomics).
// pair = [w:32][snd&63 : 6][rcv*48 : 26]; 32 zero sentinels past pair[E].
__global__ __launch_bounds__(256) void binscatter_kernel(
    const int* __restrict__ snd, const int* __restrict__ rcv,
    const float* __restrict__ ew, const int* __restrict__ off,
    long long* __restrict__ pair, int E, int NB) {
  __shared__ int cur[NBMAX];
  int tid = threadIdx.x, c = blockIdx.x;
  const int* o = off + (size_t)c * NB;
  for (int i = tid; i < NB; i += 256) cur[i] = o[i];
  __syncthreads();
  int base = c << CH2;
  int n = min(1 << CH2, E - base);
  const vi4* s4 = (const vi4*)(snd + base);
  const vi4* r4 = (const vi4*)(rcv + base);
  const vf4* w4 = (const vf4*)(ew + base);
  int n4 = n >> 2;
  for (int i = tid; i < n4; i += 256) {
    vi4 s = __builtin_nontemporal_load(&s4[i]);
    vi4 r = __builtin_nontemporal_load(&r4[i]);
    vf4 w = __builtin_nontemporal_load(&w4[i]);
    int p;
    p = atomicAdd(&cur[s.x >> BK_BITS], 1);
    __builtin_nontemporal_store(
        (long long)(((unsigned long long)(unsigned)__float_as_int(w.x) << 32)
                    | (unsigned)(((s.x & 63) << 26) | (r.x * 48))), &pair[p]);
    p = atomicAdd(&cur[s.y >> BK_BITS], 1);
    __builtin_nontemporal_store(
        (long long)(((unsigned long long)(unsigned)__float_as_int(w.y) << 32)
                    | (unsigned)(((s.y & 63) << 26) | (r.y * 48))), &pair[p]);
    p = atomicAdd(&cur[s.z >> BK_BITS], 1);
    __builtin_nontemporal_store(
        (long long)(((unsigned long long)(unsigned)__float_as_int(w.z) << 32)
                    | (unsigned)(((s.z & 63) << 26) | (r.z * 48))), &pair[p]);
    p = atomicAdd(&cur[s.w >> BK_BITS], 1);
    __builtin_nontemporal_store(
        (long long)(((unsigned long long)(unsigned)__float_as_int(w.w) << 32)
                    | (unsigned)(((s.w & 63) << 26) | (r.w * 48))), &pair[p]);
  }
  if (tid == 0) {
    for (int i = n4 << 2; i < n; ++i) {  // chunk tail
      int sv = snd[base + i];
      int p2 = atomicAdd(&cur[sv >> BK_BITS], 1);
      pair[p2] =
          (long long)(((unsigned long long)(unsigned)__float_as_int(ew[base + i]) << 32)
                      | (unsigned)(((sv & 63) << 26) | (rcv[base + i] * 48)));
    }
    if (c == 0)
      for (int z = 0; z < 32; ++z) pair[(size_t)E + z] = 0;  // sentinels
  }
}

// ---------------- flow ----------------

__device__ __forceinline__ void node_step(
    float a0, float a1, float a2, float ws, float p0, float p1, float p2,
    float ts, float dsv, float& y0, float& y1, float& y2) {
  // v_lap = -agg/deg; nrm/scale sign-invariant; -(v_lap*scale)*t = +g*scale*t
  float invdg = __builtin_amdgcn_rcpf(ws + 1e-12f);
  float g0 = a0 * invdg, g1 = a1 * invdg, g2 = a2 * invdg;
  float nrm = sqrtf(fmaf(g0, g0, fmaf(g1, g1, g2 * g2)) + EPS64F);
  float tch = ts * ts * 0.5f;  // t_sqrt^2 / N_STEPS
  float dch = dsv * dsv;
  float alp = __builtin_amdgcn_rcpf(1.0f + __expf(dch - nrm));  // sigmoid
  float scale = (nrm * alp <= 1.0f) ? alp : __builtin_amdgcn_rcpf(nrm);
  float f = scale * tch;
  float v0 = g0 * f, v1 = g1 * f, v2 = g2 * f;
  float nv = sqrtf(fmaf(v0, v0, fmaf(v1, v1, v2 * v2)));
  float cn = __cosf(nv);
  float sc = (nv > 1e-20f) ? (__sinf(nv) * __builtin_amdgcn_rcpf(nv)) : 1.0f;
  float t0 = fmaf(cn, p0, sc * v0);
  float t1 = fmaf(cn, p1, sc * v1);
  float t2 = fmaf(cn, p2, sc * v2);
  float inv = __builtin_amdgcn_rsqf(fmaf(t0, t0, fmaf(t1, t1, t2 * t2)));
  y0 = t0 * inv; y1 = t1 * inv; y2 = t2 * inv;
}

// One edge-channel item: fp32 log-map, ds_add into acc[(sl,c)].
__device__ __forceinline__ void edge_body(
    float p0, float p1, float p2, float q0, float q1, float q2,
    float w, float* __restrict__ a) {
  float cs = fminf(1.0f, fmaxf(-1.0f, fmaf(p0, q0, fmaf(p1, q1, p2 * q2))));
  float u0 = fmaf(-cs, p0, q0);
  float u1 = fmaf(-cs, p1, q1);
  float u2 = fmaf(-cs, p2, q2);
  float un2 = fmaxf(fmaf(u0, u0, fmaf(u1, u1, u2 * u2)), 1e-24f);
  float ax = fabsf(cs);
  float s = sqrtf(1.0f - ax);
  float poly = fmaf(ax, fmaf(ax, fmaf(ax, -0.0187293f, 0.0742610f),
                             -0.2121144f), 1.5707288f);
  float th = s * poly;
  float theta = (cs >= 0.0f) ? th : (PI_F - th);
  float coef = w * theta * __builtin_amdgcn_rsqf(un2);
  atomicAdd(&a[0], coef * u0);
  atomicAdd(&a[1], coef * u1);
  atomicAdd(&a[2], coef * u2);
}

// Block = 64-node bucket. LDS: p-slice (12KB) + accum (12KB) + wsum.
// Thread (c = tid&15, es = tid>>4): 16 edges/block-iter, 2x unroll.
__global__ __launch_bounds__(256) void flowb_kernel(
    const float* __restrict__ xin, const int* __restrict__ seg,
    const long long* __restrict__ pair, const float* __restrict__ tsq,
    const float* __restrict__ dsq, float* __restrict__ xout, int N) {
  __shared__ float acc[64 * 48];
  __shared__ float psh[64 * 48];
  __shared__ float wsh[64];
  int tid = threadIdx.x;
  int b = blockIdx.x;
  int n0 = b << 6;
  int nmax = min(64, N - n0);
  for (int i = tid; i < 64 * 48; i += 256) acc[i] = 0.f;
  const float* src = xin + (size_t)n0 * 48;
  int total = nmax * 48;
  for (int i = tid; i < total; i += 256) psh[i] = src[i];
  if (tid < 64) wsh[tid] = 0.f;
  int beg = seg[b], end = seg[b + 1];
  __syncthreads();
  int c = tid & 15, es = tid >> 4;
  int c3 = c * 3;
  for (int j = beg + es; j < end; j += 32) {
    int j1 = j + 16;
    // j1 may overrun into the next bucket (w forced 0, harmless add of 0)
    // or, for the last bucket, into the 32 zero sentinels.
    long long e0 = __builtin_nontemporal_load(&pair[j]);
    long long e1 = __builtin_nontemporal_load(&pair[j1]);
    float w0 = __int_as_float((int)(e0 >> 32));
    float w1 = (j1 < end) ? __int_as_float((int)(e1 >> 32)) : 0.f;
    int lo0 = (int)e0, lo1 = (int)e1;
    int r0 = lo0 & 0x03FFFFFF, r1 = lo1 & 0x03FFFFFF;
    int sl0 = (lo0 >> 26) & 63, sl1 = (lo1 >> 26) & 63;
    const float* q0p = xin + r0 + c3;
    const float* q1p = xin + r1 + c3;
    float qa0 = q0p[0], qa1 = q0p[1], qa2 = q0p[2];
    float qb0 = q1p[0], qb1 = q1p[1], qb2 = q1p[2];
    int o0 = sl0 * 48 + c3, o1 = sl1 * 48 + c3;
    edge_body(psh[o0], psh[o0 + 1], psh[o0 + 2], qa0, qa1, qa2, w0, acc + o0);
    edge_body(psh[o1], psh[o1 + 1], psh[o1 + 2], qb0, qb1, qb2, w1, acc + o1);
    if (c == 0) {
      atomicAdd(&wsh[sl0], w0);
      atomicAdd(&wsh[sl1], w1);
    }
  }
  __syncthreads();
  for (int i = tid; i < nmax * 16; i += 256) {
    int nl = i >> 4, cc = i & 15;
    int o = nl * 48 + cc * 3;
    float y0, y1, y2;
    node_step(acc[o], acc[o + 1], acc[o + 2], wsh[nl],
              psh[o], psh[o + 1], psh[o + 2], tsq[cc], dsq[cc], y0, y1, y2);
    float* d = xout + (size_t)n0 * 48 + o;
    d[0] = y0; d[1] = y1; d[2] = y2;
  }
}

static inline size_t al16(size_t x) { return (x + 15) & ~(size_t)15; }

extern "C" void kernel_launch(void* const* d_in, const int* in_sizes, int n_in,
                              void* d_out, int out_size, void* d_ws, size_t ws_size,
                              hipStream_t stream) {
  const float* nodes = (const float*)d_in[0];  // [N,16,3]
  const float* ew    = (const float*)d_in[1];  // [E]
  const float* tsq   = (const float*)d_in[2];  // [16]
  const float* dsq   = (const float*)d_in[3];  // [16]
  const int*   snd   = (const int*)d_in[4];    // [E]
  const int*   rcv   = (const int*)d_in[5];    // [E]
  float* out = (float*)d_out;

  int E = in_sizes[1];
  int N = in_sizes[0] / 48;

  int NB  = (N + 63) >> 6;           // buckets (782 @ N=50K)
  int NCH = (E + (1 << CH2) - 1) >> CH2;  // chunks (196 @ E=1.6M)

  // workspace (~24MB): cnt[NCH*NB] | off[NCH*NB] | tot[NB] | seg[NB+1]
  //                    | pair[E+32] | xtmp[N*48]
  size_t cntB = al16((size_t)NCH * NB * 4);
  size_t totB = al16((size_t)NB * 4);
  size_t segB = al16((size_t)(NB + 1) * 4);
  size_t pairB = al16((size_t)(E + 32) * 8);

  char* base = (char*)d_ws;
  int*       cnt  = (int*)base;
  int*       off  = (int*)(base + cntB);
  int*       tot  = (int*)(base + 2 * cntB);
  int*       seg  = (int*)(base + 2 * cntB + totB);
  long long* pair = (long long*)(base + 2 * cntB + totB + segB);
  float*     xtmp = (float*)(base + 2 * cntB + totB + segB + pairB);

  int nbb = (NB + 255) / 256;

  bincount_kernel<<<NCH, 256, 0, stream>>>(snd, cnt, E, NB);
  bintot_kernel<<<nbb, 256, 0, stream>>>(cnt, tot, NB, NCH);
  binbase_kernel<<<1, 64, 0, stream>>>(tot, seg, NB);
  binoff_kernel<<<nbb, 256, 0, stream>>>(cnt, seg, off, NB, NCH);
  binscatter_kernel<<<NCH, 256, 0, stream>>>(snd, rcv, ew, off, pair, E, NB);

  // step 1: nodes -> xtmp ; step 2: xtmp -> out
  flowb_kernel<<<NB, 256, 0, stream>>>(nodes, seg, pair, tsq, dsq, xtmp, N);
  flowb_kernel<<<NB, 256, 0, stream>>>(xtmp, seg, pair, tsq, dsq, out, N);
}

// Round 16
// 297.746 us; speedup vs baseline: 4.2059x; 4.2059x over previous
//
#include <hip/hip_runtime.h>
#include <math.h>

// FlowLayer: 2 steps of manifold (S^2) graph heat flow.
// N=50000 nodes, C=16 channels, D=3, E=1.6M edges.
//
// R16 = R12 (best measured, 298us) with scan fusion (9 -> 7 launches):
// Build (no global atomics): LDS-privatized histogram -> fused
// scan1A (per-node chunk fold + tile scan) -> scanB -> fused scanCD ->
// atomic-free fill packing (w, rcv*48) + 16 zero sentinels.
// Flow: R10 flowp (floor-proven ~67us/step across 6 variants: fp32 scalar,
// fp16, pk-f32, padded rows, XCD affinity, LDS-accum — all >= this):
// wave per node, lane=(k*16+c), 16 edges/wave-iter = 4 slots x 2 packed
// float2 pairs, unpadded [N][48] rows, pair packs (w, rcv*48).
//
// NOTE: |u|^2 MUST be computed from u's components (not 1-cs^2): near
// antipodal pairs 1-cs^2 cancels catastrophically -> rsq explodes (R5 bug).

constexpr float EPS64F = 2.2204460492503131e-16f;  // np.float64 eps
constexpr float PI_F   = 3.14159265358979323846f;
constexpr int   SR_BITS = 14;                 // 16384-node subranges (64KB LDS)
constexpr int   CH_BITS = 15;                 // 32768-edge chunks

typedef int   vi4 __attribute__((ext_vector_type(4)));
typedef float vf4 __attribute__((ext_vector_type(4)));
typedef float vf2 __attribute__((ext_vector_type(2)));

// ---------------- CSR build ----------------

// LDS histogram: block (c = blockIdx.x, s = blockIdx.y).
__global__ __launch_bounds__(256) void lhist_kernel(
    const int* __restrict__ snd, unsigned char* __restrict__ pos,
    int* __restrict__ partial2, int E, int NC) {
  __shared__ int h[1 << SR_BITS];
  int tid = threadIdx.x;
  int c = blockIdx.x, s = blockIdx.y;
  for (int i = tid; i < (1 << SR_BITS); i += 256) h[i] = 0;
  __syncthreads();
  int base = c << CH_BITS;
  int cnt = min(1 << CH_BITS, E - base);
  int s0 = s << SR_BITS;
  const vi4* snd4 = (const vi4*)(snd + base);  // base is 32768-aligned
  int cnt4 = cnt >> 2;
  for (int i = tid; i < cnt4; i += 256) {
    vi4 sv = snd4[i];
    int e = base + (i << 2);
    int v;
    v = sv.x - s0; if ((unsigned)v < (1u << SR_BITS)) pos[e]     = (unsigned char)atomicAdd(&h[v], 1);
    v = sv.y - s0; if ((unsigned)v < (1u << SR_BITS)) pos[e + 1] = (unsigned char)atomicAdd(&h[v], 1);
    v = sv.z - s0; if ((unsigned)v < (1u << SR_BITS)) pos[e + 2] = (unsigned char)atomicAdd(&h[v], 1);
    v = sv.w - s0; if ((unsigned)v < (1u << SR_BITS)) pos[e + 3] = (unsigned char)atomicAdd(&h[v], 1);
  }
  if (tid == 0) {  // chunk tail (cnt % 4)
    for (int i = cnt4 << 2; i < cnt; ++i) {
      int v = snd[base + i] - s0;
      if ((unsigned)v < (1u << SR_BITS))
        pos[base + i] = (unsigned char)atomicAdd(&h[v], 1);
    }
  }
  __syncthreads();
  int* dst = partial2 + ((size_t)(s * NC + c) << SR_BITS);
  for (int i = tid; i < (1 << SR_BITS); i += 256) dst[i] = h[i];
}

// Fused scan1+scanA: per-node exclusive fold over chunks (boff written in
// place) producing the node total, then tile-level shfl scan -> tile-local
// exclusive row_start + per-tile totals. Tile = block = 1024 nodes.
__global__ __launch_bounds__(1024) void scan1A_kernel(
    const int* __restrict__ partial2, int* __restrict__ boff,
    int* __restrict__ row_start, int* __restrict__ btot, int N, int NC) {
  __shared__ int wsum[16];
  int tid = threadIdx.x;
  int lane = tid & 63, wave = tid >> 6;
  int i = blockIdx.x * 1024 + tid;
  int v = 0;
  if (i < N) {
    int s = i >> SR_BITS, lv = i & ((1 << SR_BITS) - 1);
    int run = 0;
    for (int c = 0; c < NC; ++c) {
      int t = partial2[((size_t)(s * NC + c) << SR_BITS) + lv];
      boff[(size_t)c * N + i] = run;
      run += t;
    }
    v = run;  // node degree
  }
  int incl = v;
  #pragma unroll
  for (int off = 1; off < 64; off <<= 1) {
    int t = __shfl_up(incl, off, 64);
    if (lane >= off) incl += t;
  }
  if (lane == 63) wsum[wave] = incl;
  __syncthreads();
  if (wave == 0 && lane < 16) {
    int wincl = wsum[lane];
    #pragma unroll
    for (int off = 1; off < 16; off <<= 1) {
      int t = __shfl_up(wincl, off, 64);
      if (lane >= off) wincl += t;
    }
    wsum[lane] = wincl;
  }
  __syncthreads();
  int woff = (wave > 0) ? wsum[wave - 1] : 0;
  if (i < N) row_start[i] = woff + incl - v;  // tile-local exclusive
  if (tid == 0) btot[blockIdx.x] = wsum[15];
}

__global__ __launch_bounds__(64) void scanB_kernel(
    const int* __restrict__ btot, int* __restrict__ boffb,
    int* __restrict__ row_start, int nb, int N) {
  int lane = threadIdx.x;
  int v = (lane < nb) ? btot[lane] : 0;
  int incl = v;
  #pragma unroll
  for (int off = 1; off < 64; off <<= 1) {
    int t = __shfl_up(incl, off, 64);
    if (lane >= off) incl += t;
  }
  if (lane < nb) boffb[lane] = incl - v;
  if (lane == 63) row_start[N] = incl;  // grand total
}

// Fused scanC+scanD: finalize row_start; push global offsets into all
// chunk bases (coalesced).
__global__ __launch_bounds__(256) void scanCD_kernel(
    int* __restrict__ row_start, const int* __restrict__ boffb,
    int* __restrict__ boff, int N, int NC) {
  int i = blockIdx.x * 256 + threadIdx.x;
  if (i >= N) return;
  int rs = row_start[i] + boffb[i >> 10];
  row_start[i] = rs;
  for (int c = 0; c < NC; ++c) boff[(size_t)c * N + i] += rs;
}

// Atomic-free fill: slot = boff[chunk][snd] + pos[e]; packs (w, rcv*48);
// 16 zero sentinels past pair[E].
__global__ __launch_bounds__(256) void fill_kernel(
    const vi4* __restrict__ snd4, const vi4* __restrict__ rcv4,
    const vf4* __restrict__ ew4, const unsigned char* __restrict__ pos,
    const int* __restrict__ boff, long long* __restrict__ pair,
    const int* __restrict__ snd, const int* __restrict__ rcv,
    const float* __restrict__ ew, int N, int E) {
  int tid = threadIdx.x;
  int E4 = E >> 2;
  #pragma unroll
  for (int gg = 0; gg < 2; ++gg) {
    int g = blockIdx.x * 512 + gg * 256 + tid;
    if (g < E4) {
      int e = g << 2;
      const int* bc = boff + (size_t)(e >> CH_BITS) * N;  // same chunk e..e+3
      vi4 s = __builtin_nontemporal_load(&snd4[g]);
      vi4 r = __builtin_nontemporal_load(&rcv4[g]);
      vf4 w = __builtin_nontemporal_load(&ew4[g]);
      unsigned pb = *(const unsigned*)(pos + e);
      pair[bc[s.x] + (pb & 255u)] =
          (long long)(((unsigned long long)(unsigned)__float_as_int(w.x) << 32) | (unsigned)(r.x * 48));
      pair[bc[s.y] + ((pb >> 8) & 255u)] =
          (long long)(((unsigned long long)(unsigned)__float_as_int(w.y) << 32) | (unsigned)(r.y * 48));
      pair[bc[s.z] + ((pb >> 16) & 255u)] =
          (long long)(((unsigned long long)(unsigned)__float_as_int(w.z) << 32) | (unsigned)(r.z * 48));
      pair[bc[s.w] + (pb >> 24)] =
          (long long)(((unsigned long long)(unsigned)__float_as_int(w.w) << 32) | (unsigned)(r.w * 48));
    }
  }
  if (blockIdx.x == 0 && tid == 0) {
    for (int e = E4 << 2; e < E; ++e) {  // edge tail
      pair[boff[(size_t)(e >> CH_BITS) * N + snd[e]] + pos[e]] =
          (long long)(((unsigned long long)(unsigned)__float_as_int(ew[e]) << 32) | (unsigned)(rcv[e] * 48));
    }
    for (int z = 0; z < 16; ++z) pair[(size_t)E + z] = 0;  // sentinels (w=0)
  }
}

// ---------------- flow (R10 flowp, best measured) ----------------

__device__ __forceinline__ void edge_accum_pk(
    vf2 p0, vf2 p1, vf2 p2, vf2 q0, vf2 q1, vf2 q2, vf2 w,
    vf2& a0, vf2& a1, vf2& a2) {
  vf2 cs = p0 * q0 + p1 * q1 + p2 * q2;
  cs = __builtin_elementwise_min(vf2{1.f, 1.f},
       __builtin_elementwise_max(vf2{-1.f, -1.f}, cs));
  vf2 u0 = q0 - cs * p0;
  vf2 u1 = q1 - cs * p1;
  vf2 u2 = q2 - cs * p2;
  // |u|^2 from components (R5 lesson)
  vf2 un2 = __builtin_elementwise_max(u0 * u0 + u1 * u1 + u2 * u2,
                                      vf2{1e-24f, 1e-24f});
  // acos via A&S 4.4.45 (|err| <= 6.7e-5; output threshold is 2e-2)
  vf2 ax = __builtin_elementwise_abs(cs);
  vf2 s = __builtin_elementwise_sqrt(vf2{1.f, 1.f} - ax);
  vf2 poly = ((ax * -0.0187293f + 0.0742610f) * ax - 0.2121144f) * ax
             + 1.5707288f;
  vf2 th = s * poly;
  vf2 theta;
  theta.x = (cs.x >= 0.0f) ? th.x : (PI_F - th.x);
  theta.y = (cs.y >= 0.0f) ? th.y : (PI_F - th.y);
  vf2 rsq;
  rsq.x = __builtin_amdgcn_rsqf(un2.x);
  rsq.y = __builtin_amdgcn_rsqf(un2.y);
  vf2 coef = w * theta * rsq;
  a0 += coef * u0;
  a1 += coef * u1;
  a2 += coef * u2;
}

__device__ __forceinline__ void node_step(
    float a0, float a1, float a2, float ws, float p0, float p1, float p2,
    float ts, float dsv, float& y0, float& y1, float& y2) {
  // v_lap = -agg/deg; nrm/scale sign-invariant; -(v_lap*scale)*t = +g*scale*t
  float invdg = __builtin_amdgcn_rcpf(ws + 1e-12f);
  float g0 = a0 * invdg, g1 = a1 * invdg, g2 = a2 * invdg;
  float nrm = sqrtf(fmaf(g0, g0, fmaf(g1, g1, g2 * g2)) + EPS64F);
  float tch = ts * ts * 0.5f;  // t_sqrt^2 / N_STEPS
  float dch = dsv * dsv;
  float alp = __builtin_amdgcn_rcpf(1.0f + __expf(dch - nrm));  // sigmoid
  float scale = (nrm * alp <= 1.0f) ? alp : __builtin_amdgcn_rcpf(nrm);
  float f = scale * tch;
  float v0 = g0 * f, v1 = g1 * f, v2 = g2 * f;
  float nv = sqrtf(fmaf(v0, v0, fmaf(v1, v1, v2 * v2)));
  float cn = __cosf(nv);
  float sc = (nv > 1e-20f) ? (__sinf(nv) * __builtin_amdgcn_rcpf(nv)) : 1.0f;
  float t0 = fmaf(cn, p0, sc * v0);
  float t1 = fmaf(cn, p1, sc * v1);
  float t2 = fmaf(cn, p2, sc * v2);
  float inv = __builtin_amdgcn_rsqf(fmaf(t0, t0, fmaf(t1, t1, t2 * t2)));
  y0 = t0 * inv; y1 = t1 * inv; y2 = t2 * inv;
}

__global__ __launch_bounds__(256) void flowp_kernel(
    const float* __restrict__ xin, const int* __restrict__ row_start,
    const long long* __restrict__ pair, const float* __restrict__ tsq,
    const float* __restrict__ dsq, float* __restrict__ xout, int N) {
  int node = blockIdx.x * 4 + (threadIdx.x >> 6);
  if (node >= N) return;
  int lane = threadIdx.x & 63;
  int c = lane & 15;
  int k = lane >> 4;
  int c3 = c * 3;
  int beg = row_start[node];
  int end = row_start[node + 1];
  int ip = node * 48 + c3;
  float ps0 = xin[ip], ps1 = xin[ip + 1], ps2 = xin[ip + 2];
  vf2 p0 = {ps0, ps0}, p1 = {ps1, ps1}, p2 = {ps2, ps2};
  vf2 a0 = {0.f, 0.f}, a1 = {0.f, 0.f}, a2 = {0.f, 0.f}, wsv = {0.f, 0.f};
  int iters = (end - beg + 15) >> 4;
  int j = beg + k;
  for (int t = 0; t < iters; ++t, j += 16) {
    long long e0 = __builtin_nontemporal_load(&pair[j]);
    long long e1 = __builtin_nontemporal_load(&pair[j + 4]);
    long long e2 = __builtin_nontemporal_load(&pair[j + 8]);
    long long e3 = __builtin_nontemporal_load(&pair[j + 12]);
    float w0 = (j      < end) ? __int_as_float((int)(e0 >> 32)) : 0.f;
    float w1 = (j + 4  < end) ? __int_as_float((int)(e1 >> 32)) : 0.f;
    float w2 = (j + 8  < end) ? __int_as_float((int)(e2 >> 32)) : 0.f;
    float w3 = (j + 12 < end) ? __int_as_float((int)(e3 >> 32)) : 0.f;
    const float* q0p = xin + ((int)e0 + c3);
    const float* q1p = xin + ((int)e1 + c3);
    const float* q2p = xin + ((int)e2 + c3);
    const float* q3p = xin + ((int)e3 + c3);
    float qa0 = q0p[0], qa1 = q0p[1], qa2 = q0p[2];
    float qb0 = q1p[0], qb1 = q1p[1], qb2 = q1p[2];
    float qc0 = q2p[0], qc1 = q2p[1], qc2 = q2p[2];
    float qd0 = q3p[0], qd1 = q3p[1], qd2 = q3p[2];
    vf2 wA = {w0, w1}, wB = {w2, w3};
    edge_accum_pk(p0, p1, p2, vf2{qa0, qb0}, vf2{qa1, qb1}, vf2{qa2, qb2},
                  wA, a0, a1, a2);
    edge_accum_pk(p0, p1, p2, vf2{qc0, qd0}, vf2{qc1, qd1}, vf2{qc2, qd2},
                  wB, a0, a1, a2);
    wsv += wA + wB;
  }
  float A0 = a0.x + a0.y, A1 = a1.x + a1.y, A2 = a2.x + a2.y;
  float ws = wsv.x + wsv.y;
  A0 += __shfl_xor(A0, 16); A1 += __shfl_xor(A1, 16);
  A2 += __shfl_xor(A2, 16); ws += __shfl_xor(ws, 16);
  A0 += __shfl_xor(A0, 32); A1 += __shfl_xor(A1, 32);
  A2 += __shfl_xor(A2, 32); ws += __shfl_xor(ws, 32);
  if (k == 0) {
    float y0, y1, y2;
    node_step(A0, A1, A2, ws, ps0, ps1, ps2, tsq[c], dsq[c], y0, y1, y2);
    xout[ip] = y0; xout[ip + 1] = y1; xout[ip + 2] = y2;
  }
}

static inline size_t al16(size_t x) { return (x + 15) & ~(size_t)15; }

extern "C" void kernel_launch(void* const* d_in, const int* in_sizes, int n_in,
                              void* d_out, int out_size, void* d_ws, size_t ws_size,
                              hipStream_t stream) {
  const float* nodes = (const float*)d_in[0];  // [N,16,3]
  const float* ew    = (const float*)d_in[1];  // [E]
  const float* tsq   = (const float*)d_in[2];  // [16]
  const float* dsq   = (const float*)d_in[3];  // [16]
  const int*   snd   = (const int*)d_in[4];    // [E]
  const int*   rcv   = (const int*)d_in[5];    // [E]
  float* out = (float*)d_out;

  int E = in_sizes[1];
  int N = in_sizes[0] / 48;

  int NS = (N + (1 << SR_BITS) - 1) >> SR_BITS;  // node subranges (4)
  int NC = (E + (1 << CH_BITS) - 1) >> CH_BITS;  // edge chunks (49)

  // workspace (~37MB): row_start[N+4] | aux | pair[E+16] | partial2 | boff
  //                    | pos[E bytes]   ; xtmp aliases partial2 (dead after
  //                    scan1A; 12.85MB >= 9.6MB needed).
  size_t rsB   = al16((size_t)(N + 4) * 4);
  size_t auxB  = 512;
  size_t pairB = al16((size_t)(E + 16) * 8);
  size_t p2B   = al16(((size_t)NS * NC << SR_BITS) * 4);
  size_t boffB = al16((size_t)NC * N * 4);

  char* base = (char*)d_ws;
  int*           row_start = (int*)base;
  int*           btot      = (int*)(base + rsB);
  int*           boffb     = btot + 64;
  long long*     pair      = (long long*)(base + rsB + auxB);
  int*           partial2  = (int*)(base + rsB + auxB + pairB);
  int*           boff      = (int*)(base + rsB + auxB + pairB + p2B);
  unsigned char* pos       = (unsigned char*)(base + rsB + auxB + pairB + p2B + boffB);
  float*         xtmp      = (float*)partial2;  // aliased; dead after scan1A

  int E4  = E >> 2;
  int nb  = (N + 1023) / 1024;
  int nb2 = (N + 255) / 256;
  int fbk = (E4 + 511) / 512;
  int nfb = (N + 3) / 4;

  lhist_kernel<<<dim3(NC, NS), 256, 0, stream>>>(snd, pos, partial2, E, NC);
  scan1A_kernel<<<nb, 1024, 0, stream>>>(partial2, boff, row_start, btot, N, NC);
  scanB_kernel<<<1, 64, 0, stream>>>(btot, boffb, row_start, nb, N);
  scanCD_kernel<<<nb2, 256, 0, stream>>>(row_start, boffb, boff, N, NC);
  fill_kernel<<<fbk, 256, 0, stream>>>((const vi4*)snd, (const vi4*)rcv,
                                       (const vf4*)ew, pos, boff, pair,
                                       snd, rcv, ew, N, E);

  // step 1: nodes -> xtmp ; step 2: xtmp -> out (not in-place: reads neighbors)
  flowp_kernel<<<nfb, 256, 0, stream>>>(nodes, row_start, pair, tsq, dsq, xtmp, N);
  flowp_kernel<<<nfb, 256, 0, stream>>>(xtmp, row_start, pair, tsq, dsq, out, N);
}

// Round 17
// 285.008 us; speedup vs baseline: 4.3938x; 1.0447x over previous
//
#include <hip/hip_runtime.h>
#include <math.h>

// FlowLayer: 2 steps of manifold (S^2) graph heat flow.
// N=50000 nodes, C=16 channels, D=3, E=1.6M edges.
//
// R17 = R16 consolidated:
//  - CSR rows padded to multiples of 16 (pad slots zeroed by one memset) ->
//    flowp inner loop has NO guards/selects (pads are w=0,rcv=0 entries).
//  - partial2 stored as uchar (counts <= 255, same assumption as byte pos).
//  - scanB folded into scanCD (per-block LDS re-scan of <=64 tile totals).
// Build (no global atomics): LDS-privatized histogram -> fused scan1A ->
// scanCD -> atomic-free fill packing (w fp32, rcv*48).
// Flow: R10 flowp (floor-proven ~67us/step across 6 structural variants):
// wave per node, lane=(k*16+c), 16 edges/wave-iter, pk-float2 math.
//
// NOTE: |u|^2 MUST be computed from u's components (not 1-cs^2): near
// antipodal pairs 1-cs^2 cancels catastrophically -> rsq explodes (R5 bug).

constexpr float EPS64F = 2.2204460492503131e-16f;  // np.float64 eps
constexpr float PI_F   = 3.14159265358979323846f;
constexpr int   SR_BITS = 14;                 // 16384-node subranges (64KB LDS)
constexpr int   CH_BITS = 15;                 // 32768-edge chunks

typedef int   vi4 __attribute__((ext_vector_type(4)));
typedef float vf4 __attribute__((ext_vector_type(4)));
typedef float vf2 __attribute__((ext_vector_type(2)));

// ---------------- CSR build ----------------

// LDS histogram: block (c = blockIdx.x, s = blockIdx.y).
__global__ __launch_bounds__(256) void lhist_kernel(
    const int* __restrict__ snd, unsigned char* __restrict__ pos,
    unsigned char* __restrict__ partial2, int E, int NC) {
  __shared__ int h[1 << SR_BITS];
  int tid = threadIdx.x;
  int c = blockIdx.x, s = blockIdx.y;
  for (int i = tid; i < (1 << SR_BITS); i += 256) h[i] = 0;
  __syncthreads();
  int base = c << CH_BITS;
  int cnt = min(1 << CH_BITS, E - base);
  int s0 = s << SR_BITS;
  const vi4* snd4 = (const vi4*)(snd + base);  // base is 32768-aligned
  int cnt4 = cnt >> 2;
  for (int i = tid; i < cnt4; i += 256) {
    vi4 sv = snd4[i];
    int e = base + (i << 2);
    int v;
    v = sv.x - s0; if ((unsigned)v < (1u << SR_BITS)) pos[e]     = (unsigned char)atomicAdd(&h[v], 1);
    v = sv.y - s0; if ((unsigned)v < (1u << SR_BITS)) pos[e + 1] = (unsigned char)atomicAdd(&h[v], 1);
    v = sv.z - s0; if ((unsigned)v < (1u << SR_BITS)) pos[e + 2] = (unsigned char)atomicAdd(&h[v], 1);
    v = sv.w - s0; if ((unsigned)v < (1u << SR_BITS)) pos[e + 3] = (unsigned char)atomicAdd(&h[v], 1);
  }
  if (tid == 0) {  // chunk tail (cnt % 4)
    for (int i = cnt4 << 2; i < cnt; ++i) {
      int v = snd[base + i] - s0;
      if ((unsigned)v < (1u << SR_BITS))
        pos[base + i] = (unsigned char)atomicAdd(&h[v], 1);
    }
  }
  __syncthreads();
  unsigned char* dst = partial2 + ((size_t)(s * NC + c) << SR_BITS);
  for (int i = tid; i < (1 << SR_BITS); i += 256)
    dst[i] = (unsigned char)h[i];
}

// Fused scan1+scanA with row padding: per-node exclusive fold over chunks
// (boff in place, unpadded) -> degree; tile shfl-scan of PADDED degree
// (round up to 16) -> tile-local exclusive row_start + padded tile totals.
__global__ __launch_bounds__(1024) void scan1A_kernel(
    const unsigned char* __restrict__ partial2, int* __restrict__ boff,
    int* __restrict__ row_start, int* __restrict__ btot, int N, int NC) {
  __shared__ int wsum[16];
  int tid = threadIdx.x;
  int lane = tid & 63, wave = tid >> 6;
  int i = blockIdx.x * 1024 + tid;
  int vpad = 0;
  if (i < N) {
    int s = i >> SR_BITS, lv = i & ((1 << SR_BITS) - 1);
    int run = 0;
    for (int c = 0; c < NC; ++c) {
      int t = partial2[((size_t)(s * NC + c) << SR_BITS) + lv];
      boff[(size_t)c * N + i] = run;
      run += t;
    }
    vpad = (run + 15) & ~15;  // padded degree
  }
  int incl = vpad;
  #pragma unroll
  for (int off = 1; off < 64; off <<= 1) {
    int t = __shfl_up(incl, off, 64);
    if (lane >= off) incl += t;
  }
  if (lane == 63) wsum[wave] = incl;
  __syncthreads();
  if (wave == 0 && lane < 16) {
    int wincl = wsum[lane];
    #pragma unroll
    for (int off = 1; off < 16; off <<= 1) {
      int t = __shfl_up(wincl, off, 64);
      if (lane >= off) wincl += t;
    }
    wsum[lane] = wincl;
  }
  __syncthreads();
  int woff = (wave > 0) ? wsum[wave - 1] : 0;
  if (i < N) row_start[i] = woff + incl - vpad;  // tile-local exclusive
  if (tid == 0) btot[blockIdx.x] = wsum[15];
}

// scanCD (+ folded scanB): each block wave-scans the <=64 tile totals in
// LDS, then finalizes row_start and pushes offsets into all chunk bases.
__global__ __launch_bounds__(256) void scanCD_kernel(
    int* __restrict__ row_start, const int* __restrict__ btot,
    int* __restrict__ boff, int N, int NC, int nb) {
  __shared__ int bsh[64];
  int tid = threadIdx.x;
  if (tid < 64) {
    int v = (tid < nb) ? btot[tid] : 0;
    int incl = v;
    #pragma unroll
    for (int off = 1; off < 64; off <<= 1) {
      int t = __shfl_up(incl, off, 64);
      if (tid >= off) incl += t;
    }
    bsh[tid] = incl - v;  // exclusive tile offset
    if (blockIdx.x == 0 && tid == 63) row_start[N] = incl;  // padded total
  }
  __syncthreads();
  int i = blockIdx.x * 256 + tid;
  if (i >= N) return;
  int rs = row_start[i] + bsh[i >> 10];
  row_start[i] = rs;
  for (int c = 0; c < NC; ++c) boff[(size_t)c * N + i] += rs;
}

// Atomic-free fill: slot = boff[chunk][snd] + pos[e]; packs (w, rcv*48).
// Pad slots (row tails) stay zero from the memset.
__global__ __launch_bounds__(256) void fill_kernel(
    const vi4* __restrict__ snd4, const vi4* __restrict__ rcv4,
    const vf4* __restrict__ ew4, const unsigned char* __restrict__ pos,
    const int* __restrict__ boff, long long* __restrict__ pair,
    const int* __restrict__ snd, const int* __restrict__ rcv,
    const float* __restrict__ ew, int N, int E) {
  int tid = threadIdx.x;
  int E4 = E >> 2;
  #pragma unroll
  for (int gg = 0; gg < 2; ++gg) {
    int g = blockIdx.x * 512 + gg * 256 + tid;
    if (g < E4) {
      int e = g << 2;
      const int* bc = boff + (size_t)(e >> CH_BITS) * N;  // same chunk e..e+3
      vi4 s = __builtin_nontemporal_load(&snd4[g]);
      vi4 r = __builtin_nontemporal_load(&rcv4[g]);
      vf4 w = __builtin_nontemporal_load(&ew4[g]);
      unsigned pb = *(const unsigned*)(pos + e);
      pair[bc[s.x] + (pb & 255u)] =
          (long long)(((unsigned long long)(unsigned)__float_as_int(w.x) << 32) | (unsigned)(r.x * 48));
      pair[bc[s.y] + ((pb >> 8) & 255u)] =
          (long long)(((unsigned long long)(unsigned)__float_as_int(w.y) << 32) | (unsigned)(r.y * 48));
      pair[bc[s.z] + ((pb >> 16) & 255u)] =
          (long long)(((unsigned long long)(unsigned)__float_as_int(w.z) << 32) | (unsigned)(r.z * 48));
      pair[bc[s.w] + (pb >> 24)] =
          (long long)(((unsigned long long)(unsigned)__float_as_int(w.w) << 32) | (unsigned)(r.w * 48));
    }
  }
  if (blockIdx.x == 0 && tid == 0) {
    for (int e = E4 << 2; e < E; ++e) {  // edge tail
      pair[boff[(size_t)(e >> CH_BITS) * N + snd[e]] + pos[e]] =
          (long long)(((unsigned long long)(unsigned)__float_as_int(ew[e]) << 32) | (unsigned)(rcv[e] * 48));
    }
  }
}

// ---------------- flow (R10 flowp, guard-free via padded rows) ----------------

__device__ __forceinline__ void edge_accum_pk(
    vf2 p0, vf2 p1, vf2 p2, vf2 q0, vf2 q1, vf2 q2, vf2 w,
    vf2& a0, vf2& a1, vf2& a2) {
  vf2 cs = p0 * q0 + p1 * q1 + p2 * q2;
  cs = __builtin_elementwise_min(vf2{1.f, 1.f},
       __builtin_elementwise_max(vf2{-1.f, -1.f}, cs));
  vf2 u0 = q0 - cs * p0;
  vf2 u1 = q1 - cs * p1;
  vf2 u2 = q2 - cs * p2;
  // |u|^2 from components (R5 lesson)
  vf2 un2 = __builtin_elementwise_max(u0 * u0 + u1 * u1 + u2 * u2,
                                      vf2{1e-24f, 1e-24f});
  // acos via A&S 4.4.45 (|err| <= 6.7e-5; output threshold is 2e-2)
  vf2 ax = __builtin_elementwise_abs(cs);
  vf2 s = __builtin_elementwise_sqrt(vf2{1.f, 1.f} - ax);
  vf2 poly = ((ax * -0.0187293f + 0.0742610f) * ax - 0.2121144f) * ax
             + 1.5707288f;
  vf2 th = s * poly;
  vf2 theta;
  theta.x = (cs.x >= 0.0f) ? th.x : (PI_F - th.x);
  theta.y = (cs.y >= 0.0f) ? th.y : (PI_F - th.y);
  vf2 rsq;
  rsq.x = __builtin_amdgcn_rsqf(un2.x);
  rsq.y = __builtin_amdgcn_rsqf(un2.y);
  vf2 coef = w * theta * rsq;
  a0 += coef * u0;
  a1 += coef * u1;
  a2 += coef * u2;
}

__device__ __forceinline__ void node_step(
    float a0, float a1, float a2, float ws, float p0, float p1, float p2,
    float ts, float dsv, float& y0, float& y1, float& y2) {
  // v_lap = -agg/deg; nrm/scale sign-invariant; -(v_lap*scale)*t = +g*scale*t
  float invdg = __builtin_amdgcn_rcpf(ws + 1e-12f);
  float g0 = a0 * invdg, g1 = a1 * invdg, g2 = a2 * invdg;
  float nrm = sqrtf(fmaf(g0, g0, fmaf(g1, g1, g2 * g2)) + EPS64F);
  float tch = ts * ts * 0.5f;  // t_sqrt^2 / N_STEPS
  float dch = dsv * dsv;
  float alp = __builtin_amdgcn_rcpf(1.0f + __expf(dch - nrm));  // sigmoid
  float scale = (nrm * alp <= 1.0f) ? alp : __builtin_amdgcn_rcpf(nrm);
  float f = scale * tch;
  float v0 = g0 * f, v1 = g1 * f, v2 = g2 * f;
  float nv = sqrtf(fmaf(v0, v0, fmaf(v1, v1, v2 * v2)));
  float cn = __cosf(nv);
  float sc = (nv > 1e-20f) ? (__sinf(nv) * __builtin_amdgcn_rcpf(nv)) : 1.0f;
  float t0 = fmaf(cn, p0, sc * v0);
  float t1 = fmaf(cn, p1, sc * v1);
  float t2 = fmaf(cn, p2, sc * v2);
  float inv = __builtin_amdgcn_rsqf(fmaf(t0, t0, fmaf(t1, t1, t2 * t2)));
  y0 = t0 * inv; y1 = t1 * inv; y2 = t2 * inv;
}

// Wave per node; lane = k*16+c; rows padded to 16 -> no guards: pads are
// (w=0, rcv=0) entries, full-lane loads always in-bounds.
__global__ __launch_bounds__(256, 8) void flowp_kernel(
    const float* __restrict__ xin, const int* __restrict__ row_start,
    const long long* __restrict__ pair, const float* __restrict__ tsq,
    const float* __restrict__ dsq, float* __restrict__ xout, int N) {
  int node = blockIdx.x * 4 + (threadIdx.x >> 6);
  if (node >= N) return;
  int lane = threadIdx.x & 63;
  int c = lane & 15;
  int k = lane >> 4;
  int c3 = c * 3;
  int beg = row_start[node];
  int end = row_start[node + 1];
  int ip = node * 48 + c3;
  float ps0 = xin[ip], ps1 = xin[ip + 1], ps2 = xin[ip + 2];
  vf2 p0 = {ps0, ps0}, p1 = {ps1, ps1}, p2 = {ps2, ps2};
  vf2 a0 = {0.f, 0.f}, a1 = {0.f, 0.f}, a2 = {0.f, 0.f}, wsv = {0.f, 0.f};
  int iters = (end - beg) >> 4;  // exact (rows padded to 16)
  int j = beg + k;
  for (int t = 0; t < iters; ++t, j += 16) {
    long long e0 = __builtin_nontemporal_load(&pair[j]);
    long long e1 = __builtin_nontemporal_load(&pair[j + 4]);
    long long e2 = __builtin_nontemporal_load(&pair[j + 8]);
    long long e3 = __builtin_nontemporal_load(&pair[j + 12]);
    float w0 = __int_as_float((int)(e0 >> 32));
    float w1 = __int_as_float((int)(e1 >> 32));
    float w2 = __int_as_float((int)(e2 >> 32));
    float w3 = __int_as_float((int)(e3 >> 32));
    const float* q0p = xin + ((int)e0 + c3);
    const float* q1p = xin + ((int)e1 + c3);
    const float* q2p = xin + ((int)e2 + c3);
    const float* q3p = xin + ((int)e3 + c3);
    float qa0 = q0p[0], qa1 = q0p[1], qa2 = q0p[2];
    float qb0 = q1p[0], qb1 = q1p[1], qb2 = q1p[2];
    float qc0 = q2p[0], qc1 = q2p[1], qc2 = q2p[2];
    float qd0 = q3p[0], qd1 = q3p[1], qd2 = q3p[2];
    vf2 wA = {w0, w1}, wB = {w2, w3};
    edge_accum_pk(p0, p1, p2, vf2{qa0, qb0}, vf2{qa1, qb1}, vf2{qa2, qb2},
                  wA, a0, a1, a2);
    edge_accum_pk(p0, p1, p2, vf2{qc0, qd0}, vf2{qc1, qd1}, vf2{qc2, qd2},
                  wB, a0, a1, a2);
    wsv += wA + wB;
  }
  float A0 = a0.x + a0.y, A1 = a1.x + a1.y, A2 = a2.x + a2.y;
  float ws = wsv.x + wsv.y;
  A0 += __shfl_xor(A0, 16); A1 += __shfl_xor(A1, 16);
  A2 += __shfl_xor(A2, 16); ws += __shfl_xor(ws, 16);
  A0 += __shfl_xor(A0, 32); A1 += __shfl_xor(A1, 32);
  A2 += __shfl_xor(A2, 32); ws += __shfl_xor(ws, 32);
  if (k == 0) {
    float y0, y1, y2;
    node_step(A0, A1, A2, ws, ps0, ps1, ps2, tsq[c], dsq[c], y0, y1, y2);
    xout[ip] = y0; xout[ip + 1] = y1; xout[ip + 2] = y2;
  }
}

static inline size_t al16(size_t x) { return (x + 15) & ~(size_t)15; }

extern "C" void kernel_launch(void* const* d_in, const int* in_sizes, int n_in,
                              void* d_out, int out_size, void* d_ws, size_t ws_size,
                              hipStream_t stream) {
  const float* nodes = (const float*)d_in[0];  // [N,16,3]
  const float* ew    = (const float*)d_in[1];  // [E]
  const float* tsq   = (const float*)d_in[2];  // [16]
  const float* dsq   = (const float*)d_in[3];  // [16]
  const int*   snd   = (const int*)d_in[4];    // [E]
  const int*   rcv   = (const int*)d_in[5];    // [E]
  float* out = (float*)d_out;

  int E = in_sizes[1];
  int N = in_sizes[0] / 48;

  int NS = (N + (1 << SR_BITS) - 1) >> SR_BITS;  // node subranges (4)
  int NC = (E + (1 << CH_BITS) - 1) >> CH_BITS;  // edge chunks (49)

  // workspace (~34MB): row_start[N+4] | aux | pair[E+15N+64] | partial2(uchar)
  //                    | boff | pos[E bytes]  ; xtmp aliases boff (dead after
  //                    fill; 9.8MB >= 9.6MB needed).
  size_t padN  = (size_t)E + 15 * (size_t)N + 64;  // >= padded total
  size_t rsB   = al16((size_t)(N + 4) * 4);
  size_t auxB  = 512;
  size_t pairB = al16(padN * 8);
  size_t p2B   = al16((size_t)NS * NC << SR_BITS);  // uchar
  size_t boffB = al16((size_t)NC * N * 4);

  char* base = (char*)d_ws;
  int*           row_start = (int*)base;
  int*           btot      = (int*)(base + rsB);
  long long*     pair      = (long long*)(base + rsB + auxB);
  unsigned char* partial2  = (unsigned char*)(base + rsB + auxB + pairB);
  int*           boff      = (int*)(base + rsB + auxB + pairB + p2B);
  unsigned char* pos       = (unsigned char*)(base + rsB + auxB + pairB + p2B + boffB);
  float*         xtmp      = (float*)boff;  // aliased; dead after fill

  int E4  = E >> 2;
  int nb  = (N + 1023) / 1024;   // tiles (<=64 required; 49 @ N=50K)
  int nb2 = (N + 255) / 256;
  int fbk = (E4 + 511) / 512;
  int nfb = (N + 3) / 4;

  hipMemsetAsync(pair, 0, pairB, stream);  // zero pad slots (w=0, rcv=0)
  lhist_kernel<<<dim3(NC, NS), 256, 0, stream>>>(snd, pos, partial2, E, NC);
  scan1A_kernel<<<nb, 1024, 0, stream>>>(partial2, boff, row_start, btot, N, NC);
  scanCD_kernel<<<nb2, 256, 0, stream>>>(row_start, btot, boff, N, NC, nb);
  fill_kernel<<<fbk, 256, 0, stream>>>((const vi4*)snd, (const vi4*)rcv,
                                       (const vf4*)ew, pos, boff, pair,
                                       snd, rcv, ew, N, E);

  // step 1: nodes -> xtmp ; step 2: xtmp -> out (not in-place: reads neighbors)
  flowp_kernel<<<nfb, 256, 0, stream>>>(nodes, row_start, pair, tsq, dsq, xtmp, N);
  flowp_kernel<<<nfb, 256, 0, stream>>>(xtmp, row_start, pair, tsq, dsq, out, N);
}